// Round 1
// baseline (196.424 us; speedup 1.0000x reference)
//
#include <hip/hip_runtime.h>
#include <hip/hip_bf16.h>

// Problem constants
#define B_  128
#define I_  64
#define P_  16
#define T_  5
#define NT  3
#define VOCAB 100000
#define D_  64
#define NROWS (NT * VOCAB)     // 300000
#define NPAIR (B_ * I_)        // 8192 (n)
#define OUTROWS NPAIR          // 8192 output rows of 64

// ---------- bf16 helpers (manual, avoid header API drift) ----------
__device__ __forceinline__ float b2f(unsigned short h) {
    unsigned int u = ((unsigned int)h) << 16;
    return __uint_as_float(u);
}
__device__ __forceinline__ unsigned short f2b(float f) {
    unsigned int u = __float_as_uint(f);
    unsigned int r = (u + 0x7fffu + ((u >> 16) & 1u)) >> 16;   // RNE
    return (unsigned short)r;
}

typedef short short8 __attribute__((ext_vector_type(8)));
typedef float f32x4 __attribute__((ext_vector_type(4)));

// =====================================================================
// Phase 1: U[r,o] = sum_i T[r,i]*W[o,i,0] ; V[r,o] = sum_i T[r,i]*W[o,i,1]
// GEMM [NROWS x 64] x [64 x 128] via mfma_f32_16x16x32_bf16.
// Tile: 256 rows/block, 4 waves, each wave does 64 rows x 128 cols.
// =====================================================================
#define LDA 72   // padded row stride (bf16 elems): 144B = 9*16B, breaks bank stride
__global__ __launch_bounds__(256) void transform_tables(
        const float* __restrict__ tables, const float* __restrict__ convw,
        unsigned short* __restrict__ Ub, unsigned short* __restrict__ Vb) {
    __shared__ unsigned short As[256 * LDA];   // 36864 B
    __shared__ unsigned short Bs[128 * LDA];   // 18432 B
    const int tid = threadIdx.x;
    const int row0 = blockIdx.x * 256;

    // --- load A tile (256 rows x 64 fp32), convert to bf16 ---
    for (int it = 0; it < 16; ++it) {
        int v = it * 256 + tid;          // float4 index within tile
        int row = v >> 4;                // 16 float4 per row
        int c4 = (v & 15) * 4;
        float4 f;
        if (row0 + row < NROWS)
            f = *(const float4*)(tables + (size_t)(row0 + row) * 64 + c4);
        else
            f = make_float4(0.f, 0.f, 0.f, 0.f);
        unsigned short* p = &As[row * LDA + c4];
        p[0] = f2b(f.x); p[1] = f2b(f.y); p[2] = f2b(f.z); p[3] = f2b(f.w);
    }
    // --- build Bt[c][i]: c<64 -> W0[c][i], c>=64 -> W1[c-64][i] ---
    {
        int c = tid >> 1, half = tid & 1;
        for (int k = 0; k < 32; ++k) {
            int i = half * 32 + k;
            float wv = (c < 64) ? convw[c * 128 + i * 2]
                                : convw[(c - 64) * 128 + i * 2 + 1];
            Bs[c * LDA + i] = f2b(wv);
        }
    }
    __syncthreads();

    const int w = tid >> 6;          // wave 0..3
    const int lane = tid & 63;
    const int l16 = lane & 15;
    const int quad = lane >> 4;

    for (int msub = 0; msub < 4; ++msub) {
        int arow = w * 64 + msub * 16 + l16;
        short8 a0 = *(const short8*)&As[arow * LDA + quad * 8];
        short8 a1 = *(const short8*)&As[arow * LDA + 32 + quad * 8];
        for (int nsub = 0; nsub < 8; ++nsub) {
            int brow = nsub * 16 + l16;
            short8 b0 = *(const short8*)&Bs[brow * LDA + quad * 8];
            short8 b1 = *(const short8*)&Bs[brow * LDA + 32 + quad * 8];
            f32x4 acc = {0.f, 0.f, 0.f, 0.f};
            acc = __builtin_amdgcn_mfma_f32_16x16x32_bf16(a0, b0, acc, 0, 0, 0);
            acc = __builtin_amdgcn_mfma_f32_16x16x32_bf16(a1, b1, acc, 0, 0, 0);
            // C/D layout: col = lane&15, row = quad*4 + j
            int c = nsub * 16 + l16;
            int rbase = row0 + w * 64 + msub * 16 + quad * 4;
#pragma unroll
            for (int j = 0; j < 4; ++j) {
                int gr = rbase + j;
                if (gr < NROWS) {
                    if (c < 64) Ub[(size_t)gr * 64 + c] = f2b(acc[j]);
                    else        Vb[(size_t)gr * 64 + (c - 64)] = f2b(acc[j]);
                }
            }
        }
    }
}

// =====================================================================
// Phase 2: gather + add + max with the reshape-scramble folded in.
// final[nn,d] = b[d] + max_{pp,to} ( U[r_to,d] + V[r_{to+1},d] ),
//   m = pp*512 + (nn>>4), q = nn&15, r_t = type[t]*VOCAB + x[m,q,t]
// One wave per output row; lane = channel d.
// =====================================================================
__global__ __launch_bounds__(64) void gather_max(
        const int* __restrict__ path_input, const int* __restrict__ path_type,
        const unsigned short* __restrict__ Ub, const unsigned short* __restrict__ Vb,
        const float* __restrict__ bias, float* __restrict__ out) {
    const int nn = blockIdx.x;
    const int d = threadIdx.x;
    const int g = nn >> 4;
    const int q = nn & 15;
    const int tb0 = path_type[0] * VOCAB;
    const int tb1 = path_type[1] * VOCAB;
    const int tb2 = path_type[2] * VOCAB;
    const int tb3 = path_type[3] * VOCAB;
    const int tb4 = path_type[4] * VOCAB;

    float acc = -1e30f;
#pragma unroll 4
    for (int pp = 0; pp < 16; ++pp) {
        int m = pp * 512 + g;
        const int* ip = path_input + ((m * 16 + q) * 5);
        int r0 = tb0 + ip[0];
        int r1 = tb1 + ip[1];
        int r2 = tb2 + ip[2];
        int r3 = tb3 + ip[3];
        int r4 = tb4 + ip[4];
        float u0 = b2f(Ub[(size_t)r0 * 64 + d]);
        float u1 = b2f(Ub[(size_t)r1 * 64 + d]);
        float u2 = b2f(Ub[(size_t)r2 * 64 + d]);
        float u3 = b2f(Ub[(size_t)r3 * 64 + d]);
        float v1 = b2f(Vb[(size_t)r1 * 64 + d]);
        float v2 = b2f(Vb[(size_t)r2 * 64 + d]);
        float v3 = b2f(Vb[(size_t)r3 * 64 + d]);
        float v4 = b2f(Vb[(size_t)r4 * 64 + d]);
        acc = fmaxf(acc, u0 + v1);
        acc = fmaxf(acc, u1 + v2);
        acc = fmaxf(acc, u2 + v3);
        acc = fmaxf(acc, u3 + v4);
    }
    out[(size_t)nn * 64 + d] = acc + bias[d];
}

// =====================================================================
// Fallback (if workspace too small): direct fused fp32, W cached in regs.
// Correct but slow (~hundreds of us). Only used when ws_size < 76.8 MB.
// =====================================================================
__global__ __launch_bounds__(64) void fused_direct(
        const int* __restrict__ path_input, const int* __restrict__ path_type,
        const float* __restrict__ tables, const float* __restrict__ convw,
        const float* __restrict__ bias, float* __restrict__ out) {
    const int nn = blockIdx.x;
    const int o = threadIdx.x;
    const int g = nn >> 4;
    const int q = nn & 15;
    float w0[64], w1[64];
#pragma unroll
    for (int i = 0; i < 64; ++i) {
        w0[i] = convw[o * 128 + i * 2];
        w1[i] = convw[o * 128 + i * 2 + 1];
    }
    int tb[5];
#pragma unroll
    for (int t = 0; t < 5; ++t) tb[t] = path_type[t] * VOCAB;
    __shared__ float emb[5][64];
    float acc = -1e30f;
    for (int pp = 0; pp < 16; ++pp) {
        int m = pp * 512 + g;
        const int* ip = path_input + ((m * 16 + q) * 5);
        __syncthreads();
#pragma unroll
        for (int t = 0; t < 5; ++t)
            emb[t][o] = tables[(size_t)(tb[t] + ip[t]) * 64 + o];
        __syncthreads();
#pragma unroll
        for (int to = 0; to < 4; ++to) {
            float s = 0.f;
#pragma unroll
            for (int i = 0; i < 64; ++i)
                s += w0[i] * emb[to][i] + w1[i] * emb[to + 1][i];
            acc = fmaxf(acc, s);
        }
    }
    out[(size_t)nn * 64 + o] = acc + bias[o];
}

extern "C" void kernel_launch(void* const* d_in, const int* in_sizes, int n_in,
                              void* d_out, int out_size, void* d_ws, size_t ws_size,
                              hipStream_t stream) {
    const int*   path_input = (const int*)d_in[0];
    const int*   path_type  = (const int*)d_in[1];
    const float* tables     = (const float*)d_in[2];
    const float* convw      = (const float*)d_in[3];
    const float* convb      = (const float*)d_in[4];
    float* out = (float*)d_out;

    const size_t need = (size_t)2 * NROWS * 64 * sizeof(unsigned short); // 76.8 MB
    if (ws_size >= need) {
        unsigned short* Ub = (unsigned short*)d_ws;
        unsigned short* Vb = Ub + (size_t)NROWS * 64;
        transform_tables<<<(NROWS + 255) / 256, 256, 0, stream>>>(tables, convw, Ub, Vb);
        gather_max<<<OUTROWS, 64, 0, stream>>>(path_input, path_type, Ub, Vb, convb, out);
    } else {
        fused_direct<<<OUTROWS, 64, 0, stream>>>(path_input, path_type, tables, convw, convb, out);
    }
}

// Round 2
// 181.375 us; speedup vs baseline: 1.0830x; 1.0830x over previous
//
#include <hip/hip_runtime.h>
#include <hip/hip_bf16.h>

// Problem constants
#define B_  128
#define I_  64
#define P_  16
#define T_  5
#define NT  3
#define VOCAB 100000
#define D_  64
#define NROWS (NT * VOCAB)     // 300000
#define NPAIR (B_ * I_)        // 8192 (n)
#define OUTROWS NPAIR          // 8192 output rows of 64

// ---------- bf16 helpers ----------
__device__ __forceinline__ float b2f(unsigned short h) {
    return __uint_as_float(((unsigned int)h) << 16);
}
__device__ __forceinline__ unsigned short f2b(float f) {
    unsigned int u = __float_as_uint(f);
    return (unsigned short)((u + 0x7fffu + ((u >> 16) & 1u)) >> 16);   // RNE
}

typedef short short8 __attribute__((ext_vector_type(8)));
typedef float f32x4 __attribute__((ext_vector_type(4)));

// =====================================================================
// Phase 1: UV[r][c] for c<64: U = T[r,:]·W0[c,:] ; c>=64: V = T[r,:]·W1[c-64,:]
// mfma_f32_16x16x32_bf16 with weights as FIRST operand so D-rows = channels:
// lane stores 4 consecutive channels (8 B) per tile. A loaded direct from
// global (no LDS); only the 18 KB weight tile is staged in LDS.
// =====================================================================
#define LDB 72   // padded row stride for weight tile (bf16 elems)
__global__ __launch_bounds__(256) void transform_tables(
        const float* __restrict__ tables, const float* __restrict__ convw,
        unsigned short* __restrict__ UV) {
    __shared__ unsigned short Bt[128 * LDB];   // 18432 B
    const int tid = threadIdx.x;

    // Bt[c][i]: c<64 -> W[c][i][0], c>=64 -> W[c-64][i][1]; convw[o*128+i*2+k]
    {
        int c = tid >> 1, half = tid & 1;
        const float* wp = (c < 64) ? (convw + c * 128) : (convw + (c - 64) * 128 + 1);
#pragma unroll
        for (int k = 0; k < 32; ++k) {
            int i = half * 32 + k;
            Bt[c * LDB + i] = f2b(wp[i * 2]);
        }
    }
    __syncthreads();

    const int w = tid >> 6;          // wave 0..3
    const int lane = tid & 63;
    const int l16 = lane & 15;
    const int quad = lane >> 4;

    // weight fragments, loaded once, reused for 4 row-tiles
    short8 bf0[8], bf1[8];
#pragma unroll
    for (int ns = 0; ns < 8; ++ns) {
        bf0[ns] = *(const short8*)&Bt[(ns * 16 + l16) * LDB + quad * 8];
        bf1[ns] = *(const short8*)&Bt[(ns * 16 + l16) * LDB + 32 + quad * 8];
    }

    const int rowblk = blockIdx.x * 256 + w * 64;
    for (int tile = 0; tile < 4; ++tile) {
        int row = rowblk + tile * 16 + l16;
        int rowc = row < NROWS ? row : NROWS - 1;
        const float* ap = tables + (size_t)rowc * 64 + quad * 8;
        float4 fa = *(const float4*)(ap);
        float4 fb = *(const float4*)(ap + 4);
        float4 fc = *(const float4*)(ap + 32);
        float4 fd = *(const float4*)(ap + 36);
        short8 a0, a1;
        a0[0] = (short)f2b(fa.x); a0[1] = (short)f2b(fa.y);
        a0[2] = (short)f2b(fa.z); a0[3] = (short)f2b(fa.w);
        a0[4] = (short)f2b(fb.x); a0[5] = (short)f2b(fb.y);
        a0[6] = (short)f2b(fb.z); a0[7] = (short)f2b(fb.w);
        a1[0] = (short)f2b(fc.x); a1[1] = (short)f2b(fc.y);
        a1[2] = (short)f2b(fc.z); a1[3] = (short)f2b(fc.w);
        a1[4] = (short)f2b(fd.x); a1[5] = (short)f2b(fd.y);
        a1[6] = (short)f2b(fd.z); a1[7] = (short)f2b(fd.w);

        f32x4 acc[8];
#pragma unroll
        for (int ns = 0; ns < 8; ++ns) acc[ns] = (f32x4){0.f, 0.f, 0.f, 0.f};
#pragma unroll
        for (int ns = 0; ns < 8; ++ns) {
            acc[ns] = __builtin_amdgcn_mfma_f32_16x16x32_bf16(bf0[ns], a0, acc[ns], 0, 0, 0);
            acc[ns] = __builtin_amdgcn_mfma_f32_16x16x32_bf16(bf1[ns], a1, acc[ns], 0, 0, 0);
        }
        // D layout: col(lane&15)=table row, row(quad*4+j)=channel -> 8B stores
        if (row < NROWS) {
            unsigned short* op = UV + (size_t)row * 128 + quad * 4;
#pragma unroll
            for (int ns = 0; ns < 8; ++ns) {
                unsigned long long pk =
                      (unsigned long long)f2b(acc[ns][0])
                    | ((unsigned long long)f2b(acc[ns][1]) << 16)
                    | ((unsigned long long)f2b(acc[ns][2]) << 32)
                    | ((unsigned long long)f2b(acc[ns][3]) << 48);
                *(unsigned long long*)(op + ns * 16) = pk;
            }
        }
    }
}

// =====================================================================
// Phase 2: final[nn,d] = b[d] + max_{pp,to} ( U[r_to,d] + V[r_{to+1},d] )
//   m = pp*512 + (nn>>4), q = nn&15, r_t = type[t]*VOCAB + x[m,q,t]
// 256-thr blocks (4 nn), indices staged in LDS, all gathers independent.
// =====================================================================
__global__ __launch_bounds__(256) void gather_max(
        const int* __restrict__ path_input, const int* __restrict__ path_type,
        const unsigned short* __restrict__ UV, const float* __restrict__ bias,
        float* __restrict__ out) {
    __shared__ int ridx[4][16][5];
    const int tid = threadIdx.x;
    const int nn0 = blockIdx.x * 4;
    for (int i = tid; i < 320; i += 256) {
        int ln = i / 80, j = i - ln * 80;
        int pp = j / 5, t = j - pp * 5;
        int nn = nn0 + ln;
        int g = nn >> 4, q = nn & 15;
        int addr = ((pp * 512 + g) * 16 + q) * 5 + t;
        ridx[ln][pp][t] = (path_type[t] * VOCAB + path_input[addr]) * 128;
    }
    __syncthreads();

    const int w = tid >> 6, d = tid & 63;
    const int nn = nn0 + w;
    float acc = -1e30f;
#pragma unroll 4
    for (int pp = 0; pp < 16; ++pp) {
        int r0 = ridx[w][pp][0];
        int r1 = ridx[w][pp][1];
        int r2 = ridx[w][pp][2];
        int r3 = ridx[w][pp][3];
        int r4 = ridx[w][pp][4];
        float u0 = b2f(UV[r0 + d]);
        float u1 = b2f(UV[r1 + d]);
        float u2 = b2f(UV[r2 + d]);
        float u3 = b2f(UV[r3 + d]);
        float v1 = b2f(UV[r1 + 64 + d]);
        float v2 = b2f(UV[r2 + 64 + d]);
        float v3 = b2f(UV[r3 + 64 + d]);
        float v4 = b2f(UV[r4 + 64 + d]);
        acc = fmaxf(acc, u0 + v1);
        acc = fmaxf(acc, u1 + v2);
        acc = fmaxf(acc, u2 + v3);
        acc = fmaxf(acc, u3 + v4);
    }
    out[(size_t)nn * 64 + d] = acc + bias[d];
}

// =====================================================================
// Fallback (if workspace too small): direct fused fp32.
// =====================================================================
__global__ __launch_bounds__(64) void fused_direct(
        const int* __restrict__ path_input, const int* __restrict__ path_type,
        const float* __restrict__ tables, const float* __restrict__ convw,
        const float* __restrict__ bias, float* __restrict__ out) {
    const int nn = blockIdx.x;
    const int o = threadIdx.x;
    const int g = nn >> 4;
    const int q = nn & 15;
    float w0[64], w1[64];
#pragma unroll
    for (int i = 0; i < 64; ++i) {
        w0[i] = convw[o * 128 + i * 2];
        w1[i] = convw[o * 128 + i * 2 + 1];
    }
    int tb[5];
#pragma unroll
    for (int t = 0; t < 5; ++t) tb[t] = path_type[t] * VOCAB;
    __shared__ float emb[5][64];
    float acc = -1e30f;
    for (int pp = 0; pp < 16; ++pp) {
        int m = pp * 512 + g;
        const int* ip = path_input + ((m * 16 + q) * 5);
        __syncthreads();
#pragma unroll
        for (int t = 0; t < 5; ++t)
            emb[t][o] = tables[(size_t)(tb[t] + ip[t]) * 64 + o];
        __syncthreads();
#pragma unroll
        for (int to = 0; to < 4; ++to) {
            float s = 0.f;
#pragma unroll
            for (int i = 0; i < 64; ++i)
                s += w0[i] * emb[to][i] + w1[i] * emb[to + 1][i];
            acc = fmaxf(acc, s);
        }
    }
    out[(size_t)nn * 64 + o] = acc + bias[o];
}

extern "C" void kernel_launch(void* const* d_in, const int* in_sizes, int n_in,
                              void* d_out, int out_size, void* d_ws, size_t ws_size,
                              hipStream_t stream) {
    const int*   path_input = (const int*)d_in[0];
    const int*   path_type  = (const int*)d_in[1];
    const float* tables     = (const float*)d_in[2];
    const float* convw      = (const float*)d_in[3];
    const float* convb      = (const float*)d_in[4];
    float* out = (float*)d_out;

    const size_t need = (size_t)NROWS * 128 * sizeof(unsigned short); // 76.8 MB
    if (ws_size >= need) {
        unsigned short* UV = (unsigned short*)d_ws;
        transform_tables<<<(NROWS + 255) / 256, 256, 0, stream>>>(tables, convw, UV);
        gather_max<<<OUTROWS / 4, 256, 0, stream>>>(path_input, path_type, UV, convb, out);
    } else {
        fused_direct<<<OUTROWS, 64, 0, stream>>>(path_input, path_type, tables, convw, convb, out);
    }
}